// Round 1
// baseline (137.825 us; speedup 1.0000x reference)
//
#include <hip/hip_runtime.h>
#include <hip/hip_fp16.h>

// NeuronToSpatialGrid R4: 32x32x16 MFMA, frag-order operand layouts, 128x128 block,
// 1 block/CU, triple-buffered LDS staging via global_load_lds with counted vmcnt
// (one raw s_barrier per K-128 round), EY A-frags streamed from L2 (coalesced).

typedef __attribute__((ext_vector_type(8))) _Float16 half8;
typedef __attribute__((ext_vector_type(2))) _Float16 half2v;
typedef __attribute__((ext_vector_type(4))) float floatx4;
typedef __attribute__((ext_vector_type(16))) float floatx16;

#define NB 4
#define NN 4096
#define NE 256
#define NP 4096

#if defined(__has_builtin)
#if __has_builtin(__builtin_amdgcn_fdot2)
#define HAVE_FDOT2 1
#endif
#endif

__device__ inline float sum8(half8 v, float s) {
#ifdef HAVE_FDOT2
    half2v one; one[0] = (_Float16)1.0f; one[1] = (_Float16)1.0f;
    half2v* p = (half2v*)&v;
#pragma unroll
    for (int j = 0; j < 4; j++) s = __builtin_amdgcn_fdot2(p[j], one, s, false);
#else
#pragma unroll
    for (int j = 0; j < 8; j++) s += (float)v[j];
#endif
    return s;
}

#define MFMA32(a, bb, c) __builtin_amdgcn_mfma_f32_32x32x16_f16(a, bb, c, 0, 0, 0)

__device__ __forceinline__ void gload_lds16(const void* g, void* l) {
    __builtin_amdgcn_global_load_lds((const __attribute__((address_space(1))) void*)g,
                                     (__attribute__((address_space(3))) void*)l, 16, 0, 0);
}

// ---------- kernel 1: F [B][N][E] f32 -> FT32 in 32x32x16 B-frag order:
// idx = (((b*256 + kb)*8 + eb)*64 + l)*8 + j  holds F[b][kb*16 + (l>>5)*8 + j][eb*32 + (l&31)]
__global__ __launch_bounds__(256) void feat_transpose(const float* __restrict__ in,
                                                      __half* __restrict__ ft) {
    __shared__ float tile[128][33];
    const int b   = blockIdx.z;
    const int n0  = blockIdx.x * 128;     // 8 kb per block
    const int eb  = blockIdx.y;           // e0 = eb*32
    const int tid = threadIdx.x;
    const int rn = tid >> 3, re = (tid & 7) * 4;
#pragma unroll
    for (int p = 0; p < 4; p++) {
        const int n = p * 32 + rn;
        float4 v = *(const float4*)&in[(size_t)(b * NN + n0 + n) * NE + eb * 32 + re];
        tile[n][re] = v.x; tile[n][re + 1] = v.y; tile[n][re + 2] = v.z; tile[n][re + 3] = v.w;
    }
    __syncthreads();
#pragma unroll
    for (int i = 0; i < 2; i++) {
        const int c = i * 256 + tid;
        const int l = c & 63, kb_l = c >> 6;        // 0..7
        const int nbase = kb_l * 16 + ((l >> 5) << 3);
        const int col = l & 31;
        __half hh[8];
#pragma unroll
        for (int j = 0; j < 8; j++) hh[j] = __float2half_rn(tile[nbase + j][col]);
        const size_t idx = ((((size_t)b * 256 + (size_t)blockIdx.x * 8 + kb_l) * 8 + eb) * 64 + l) * 8;
        *(uint4*)&ft[idx] = *(const uint4*)hh;
    }
}

// ---------- kernel 2: EY in 32x32x16 A-frag order:
// idx = (((b*256 + kb)*2 + rt)*64 + l)*8 + j holds exp(-50*(r/63 - y_k)^2),
//   r = rt*32 + (l&31), k = kb*16 + (l>>5)*8 + j
__global__ __launch_bounds__(256) void eyf_kernel(const float* __restrict__ pos,
                                                  __half* __restrict__ EYf) {
    const int idx = blockIdx.x * 256 + threadIdx.x;
    const int j  = idx & 7;
    const int l  = (idx >> 3) & 63;
    const int rt = (idx >> 9) & 1;
    const int kb = (idx >> 10) & 255;
    const int b  = idx >> 18;
    const int r = rt * 32 + (l & 31);
    const int k = kb * 16 + ((l >> 5) << 3) + j;
    const float y = pos[((size_t)b * NN + k) * 2 + 1];
    const float d = (float)r * (1.0f / 63.0f) - y;
    EYf[idx] = __float2half_rn(__expf(d * d * -50.0f));
}

// ---------- kernel 3: fused GEMM. grid 256 (1 block/CU), 512 thr = 8 waves.
// Block 128m x 128e; wave (g = m-half, h = e-quarter) owns 64m x 32e (2 MFMA tiles).
// K-loop: 32 rounds of K=128; B staged in 3 LDS buffers (global_load_lds, linear),
// one raw s_barrier + counted vmcnt per round; EY from L2, 4 K16-steps ahead in regs.
__global__ __launch_bounds__(512, 2) void nw_gemm(const __half* __restrict__ FT,
                                                  const __half* __restrict__ EYf,
                                                  const float* __restrict__ pos,
                                                  float* __restrict__ out) {
    __shared__ __half Bs[3][16384];      // 3 x 32 KB (8 kb x 4 eb x 64 l x 8 j per buf)
    __shared__ __half ex_s[2][4096];     // 16 KB: ex per gx in {2*mblk, 2*mblk+1}
    __shared__ float S_s[128];
    __shared__ float Sinv_s[128];

    const int bid  = blockIdx.x;
    const int xcd  = bid & 7;            // (b, et) pinned per XCD: FT-half 1MB + EY 0.5MB in L2
    const int b    = xcd >> 1;
    const int et   = xcd & 1;
    const int mblk = bid >> 3;           // 0..31
    const int tid  = threadIdx.x;
    const int wave = tid >> 6, lane = tid & 63;
    const int g = wave & 1;              // m-half
    const int h = wave >> 1;             // e-quarter 0..3 (duty waves h<2 sum rt=h)
    const int hi8 = (lane >> 5) << 3;
    const bool duty = (h < 2);

    // staging source: wave stages kb_l = wave, chunks i=0..3 (eb = et*4 + i)
    const __half* ftw = FT + ((size_t)b * 2048 + (size_t)wave * 8 + et * 4) * 512 + (size_t)lane * 8;
    // EY frag source
    const __half* eyL = EYf + ((size_t)b << 18) + (size_t)lane * 8;
    const __half* ex_row = ex_s[g];

#define STAGE(rr, sb) do {                                             \
        const __half* s_ = ftw + (size_t)(rr) * 32768;                 \
        __half* d_ = &Bs[sb][wave * 2048];                             \
        gload_lds16(s_,        d_);                                    \
        gload_lds16(s_ + 512,  d_ + 512);                              \
        gload_lds16(s_ + 1024, d_ + 1024);                             \
        gload_lds16(s_ + 1536, d_ + 1536);                             \
    } while (0)

    // ---- prologue: issue EY t=0..3 and stages for rounds 0,1 (latency hidden under ex compute)
    half8 eyr[4][2];
#pragma unroll
    for (int t = 0; t < 4; ++t) {
        eyr[t][0] = *(const half8*)(eyL + (size_t)(t * 2 + 0) * 512);
        eyr[t][1] = *(const half8*)(eyL + (size_t)(t * 2 + 1) * 512);
    }
    STAGE(0, 0);
    STAGE(1, 1);

    {   // ex_s: 2 gx rows x 4096 exps
        const float* pb = pos + (size_t)b * NN * 2;
        const float gx0 = (float)(mblk * 2)     * (1.0f / 63.0f);
        const float gx1 = (float)(mblk * 2 + 1) * (1.0f / 63.0f);
        for (int k = tid; k < NN; k += 512) {
            const float x = pb[2 * k];
            const float d0 = gx0 - x, d1 = gx1 - x;
            ex_s[0][k] = __float2half_rn(__expf(d0 * d0 * -50.0f));
            ex_s[1][k] = __float2half_rn(__expf(d1 * d1 * -50.0f));
        }
    }
    __syncthreads();   // ex_s ready (one-time full drain, prologue only)

    floatx16 acc0 = {}, acc1 = {};       // rt=0 (rows 0..31), rt=1 (rows 32..63)
    float sdot = 0.f;

    const __half* bb0 = &Bs[0][(h * 64 + lane) * 8];   // frag: (s*4+h)*512 + lane*8

    for (int r = 0; r < 32; ++r) {
        const __half* bb = &Bs[r % 3][(h * 64 + lane) * 8];
        __builtin_amdgcn_sched_barrier(0);
        // counted wait: allow {8 EY prefetches, 4 stage(r+1)} in flight; forces stage(r) done
        if (r == 31) { asm volatile("s_waitcnt vmcnt(8)" ::: "memory"); }
        else         { asm volatile("s_waitcnt vmcnt(12)" ::: "memory"); }
        __builtin_amdgcn_s_barrier();
        __builtin_amdgcn_sched_barrier(0);
        if (r < 30) { STAGE(r + 2, (r + 2) % 3); }   // post-barrier: round r-1 readers are done
        __builtin_amdgcn_sched_barrier(0);
#pragma unroll
        for (int s = 0; s < 8; ++s) {
            const int t = r * 8 + s;
            const int slot = s & 3;
            half8 ey0 = eyr[slot][0], ey1 = eyr[slot][1];
            {   // roll EY prefetch 4 steps ahead
                const int tn = (t + 4) & 255;
                eyr[slot][0] = *(const half8*)(eyL + (size_t)(tn * 2 + 0) * 512);
                eyr[slot][1] = *(const half8*)(eyL + (size_t)(tn * 2 + 1) * 512);
            }
            const half8 ex8 = *(const half8*)(ex_row + t * 16 + hi8);
            const half8 a0 = ex8 * ey0;
            const half8 a1 = ex8 * ey1;
            if (duty) { const half8 av = (h == 0) ? a0 : a1; sdot = sum8(av, sdot); }
            const half8 bf = *(const half8*)(bb + s * 2048);
            __builtin_amdgcn_s_setprio(1);
            acc0 = MFMA32(a0, bf, acc0);
            acc1 = MFMA32(a1, bf, acc1);
            __builtin_amdgcn_s_setprio(0);
        }
    }
    (void)bb0;

    // ---- row sums: duty wave (g,h<2) owns rows r = h*32 + (lane&31) of m-half g
    if (duty) {
        float s = sdot;
        s += __shfl_xor(s, 32, 64);
        if (lane < 32) S_s[g * 64 + h * 32 + lane] = s;
    }
    __syncthreads();
    if (tid < 128) Sinv_s[tid] = 1.0f / (S_s[tid] + 1e-8f);
    __syncthreads();

    // ---- epilogue: normalize + store. D layout: col(e)=lane&31, row=(reg&3)+8*(reg>>2)+4*(lane>>5)
    float* outb = out + (size_t)b * NE * NP;
    const int e   = et * 128 + h * 32 + (lane & 31);
    const int p00 = mblk * 128 + g * 64;
    float* orow = outb + (size_t)e * NP;
#pragma unroll
    for (int rt = 0; rt < 2; ++rt) {
        const floatx16 a = rt ? acc1 : acc0;
#pragma unroll
        for (int q = 0; q < 4; ++q) {
            const int pr = rt * 32 + q * 8 + ((lane >> 5) << 2);
            const floatx4 sv = *(const floatx4*)&Sinv_s[g * 64 + pr];
            floatx4 o;
            o.x = a[q * 4 + 0] * sv.x; o.y = a[q * 4 + 1] * sv.y;
            o.z = a[q * 4 + 2] * sv.z; o.w = a[q * 4 + 3] * sv.w;
            *(floatx4*)&orow[p00 + pr] = o;
        }
    }
#undef STAGE
}

extern "C" void kernel_launch(void* const* d_in, const int* in_sizes, int n_in,
                              void* d_out, int out_size, void* d_ws, size_t ws_size,
                              hipStream_t stream) {
    const float* feat = (const float*)d_in[0];   // [4][4096][256] f32
    const float* pos  = (const float*)d_in[1];   // [4][4096][2]  f32
    float* out = (float*)d_out;                  // [4][256][4096] f32
    __half* FT  = (__half*)d_ws;                                       // 8.39 MB (frag order)
    __half* EYf = (__half*)((char*)d_ws + (size_t)NB * NE * NN * 2);   // +2.10 MB (frag order)

    hipLaunchKernelGGL(feat_transpose, dim3(NN / 128, NE / 32, NB), dim3(256), 0, stream,
                       feat, FT);
    hipLaunchKernelGGL(eyf_kernel, dim3((NB << 18) / 256), dim3(256), 0, stream,
                       pos, EYf);
    hipLaunchKernelGGL(nw_gemm, dim3(256), dim3(512), 0, stream,
                       FT, EYf, pos, out);
}

// Round 2
// 128.214 us; speedup vs baseline: 1.0750x; 1.0750x over previous
//
#include <hip/hip_runtime.h>
#include <hip/hip_fp16.h>

// NeuronToSpatialGrid R5: 32x32x16 MFMA, frag-order layouts (proven conflict-free),
// 512 blocks x 512 thr (2 blocks/CU, 4 waves/SIMD, 2 barrier domains).
// Block tile 128m x 64e; 8 waves = 2 m-halves x 4-way K-split (wave 64m x 64e).
// K-64 rounds, triple-buffered B+EY staging via global_load_lds (2 loads/thr/round),
// one s_barrier + counted vmcnt(2) per round. Inner loop has ZERO global loads.

typedef __attribute__((ext_vector_type(8))) _Float16 half8;
typedef __attribute__((ext_vector_type(2))) _Float16 half2v;
typedef __attribute__((ext_vector_type(4))) float floatx4;
typedef __attribute__((ext_vector_type(16))) float floatx16;

#define NB 4
#define NN 4096
#define NE 256
#define NP 4096

#if defined(__has_builtin)
#if __has_builtin(__builtin_amdgcn_fdot2)
#define HAVE_FDOT2 1
#endif
#endif

__device__ inline float sum8(half8 v, float s) {
#ifdef HAVE_FDOT2
    half2v one; one[0] = (_Float16)1.0f; one[1] = (_Float16)1.0f;
    half2v* p = (half2v*)&v;
#pragma unroll
    for (int j = 0; j < 4; j++) s = __builtin_amdgcn_fdot2(p[j], one, s, false);
#else
#pragma unroll
    for (int j = 0; j < 8; j++) s += (float)v[j];
#endif
    return s;
}

#define MFMA32(a, bb, c) __builtin_amdgcn_mfma_f32_32x32x16_f16(a, bb, c, 0, 0, 0)

__device__ __forceinline__ void gload_lds16(const void* g, void* l) {
    __builtin_amdgcn_global_load_lds((const __attribute__((address_space(1))) void*)g,
                                     (__attribute__((address_space(3))) void*)l, 16, 0, 0);
}

// ---------- kernel 1: F [B][N][E] f32 -> FT in 32x32x16 B-frag order:
// idx = (((b*256 + kb)*8 + eb)*64 + l)*8 + j  holds F[b][kb*16 + (l>>5)*8 + j][eb*32 + (l&31)]
__global__ __launch_bounds__(256) void feat_transpose(const float* __restrict__ in,
                                                      __half* __restrict__ ft) {
    __shared__ float tile[128][33];
    const int b   = blockIdx.z;
    const int n0  = blockIdx.x * 128;     // 8 kb per block
    const int eb  = blockIdx.y;           // e0 = eb*32
    const int tid = threadIdx.x;
    const int rn = tid >> 3, re = (tid & 7) * 4;
#pragma unroll
    for (int p = 0; p < 4; p++) {
        const int n = p * 32 + rn;
        float4 v = *(const float4*)&in[(size_t)(b * NN + n0 + n) * NE + eb * 32 + re];
        tile[n][re] = v.x; tile[n][re + 1] = v.y; tile[n][re + 2] = v.z; tile[n][re + 3] = v.w;
    }
    __syncthreads();
#pragma unroll
    for (int i = 0; i < 2; i++) {
        const int c = i * 256 + tid;
        const int l = c & 63, kb_l = c >> 6;        // 0..7
        const int nbase = kb_l * 16 + ((l >> 5) << 3);
        const int col = l & 31;
        __half hh[8];
#pragma unroll
        for (int j = 0; j < 8; j++) hh[j] = __float2half_rn(tile[nbase + j][col]);
        const size_t idx = ((((size_t)b * 256 + (size_t)blockIdx.x * 8 + kb_l) * 8 + eb) * 64 + l) * 8;
        *(uint4*)&ft[idx] = *(const uint4*)hh;
    }
}

// ---------- kernel 2: EY in 32x32x16 A-frag order:
// idx = (((b*256 + kb)*2 + rt)*64 + l)*8 + j holds exp(-50*(r/63 - y_k)^2),
//   r = rt*32 + (l&31), k = kb*16 + (l>>5)*8 + j
__global__ __launch_bounds__(256) void eyf_kernel(const float* __restrict__ pos,
                                                  __half* __restrict__ EYf) {
    const int idx = blockIdx.x * 256 + threadIdx.x;
    const int j  = idx & 7;
    const int l  = (idx >> 3) & 63;
    const int rt = (idx >> 9) & 1;
    const int kb = (idx >> 10) & 255;
    const int b  = idx >> 18;
    const int r = rt * 32 + (l & 31);
    const int k = kb * 16 + ((l >> 5) << 3) + j;
    const float y = pos[((size_t)b * NN + k) * 2 + 1];
    const float d = (float)r * (1.0f / 63.0f) - y;
    EYf[idx] = __float2half_rn(__expf(d * d * -50.0f));
}

// ---------- kernel 3: fused GEMM.
__global__ __launch_bounds__(512, 4) void nw_gemm(const __half* __restrict__ FT,
                                                  const __half* __restrict__ EYf,
                                                  const float* __restrict__ pos,
                                                  float* __restrict__ out) {
    __shared__ __half Bs[3][4096];       // 24 KB: per round [4 kb][2 eb][64 l][8 j]
    __shared__ __half EYs[3][4096];      // 24 KB: per round [4 kb][2 rt][64 l][8 j]
    __shared__ __half ex_s[2][4096];     // 16 KB: ex rows for gx = 2*mblk, 2*mblk+1
    __shared__ float S_s[4][128];        // per-kw row-sum partials
    __shared__ float Sinv_s[128];

    const int bid  = blockIdx.x;
    const int xcd  = bid & 7;            // pin (b, e-half) per XCD: 1.5 MB L2 set
    const int b    = xcd >> 1;
    const int etp  = xcd & 1;
    const int rest = bid >> 3;           // 0..63
    const int et   = etp * 2 + (rest & 1);   // e-quarter 0..3 (64 e each)
    const int mblk = rest >> 1;          // 0..31 (128 p rows each)
    const int tid  = threadIdx.x;
    const int wave = tid >> 6, lane = tid & 63;
    const int g   = wave & 1;            // m-half (gx = 2*mblk + g)
    const int kw  = wave >> 1;           // k-quarter 0..3 within each round
    const int hi8 = (lane >> 5) << 3;

    // staging sources (frag order => linear 16B/lane, wave-uniform LDS dest)
    const __half* ft_t = FT + ((size_t)(b * 256 + (tid >> 7)) * 8 + et * 2) * 512
                            + (size_t)(tid & 127) * 8;
    const __half* ey_t = EYf + ((size_t)b << 18) + (size_t)tid * 8;
    const int bdst = (tid >> 7) * 1024 + (tid & 127) * 8;
    const int edst = tid * 8;

#define STAGE(rr, sb_) do {                                            \
        gload_lds16(ft_t + (size_t)(rr) * 16384, &Bs[sb_][bdst]);      \
        gload_lds16(ey_t + (size_t)(rr) * 4096,  &EYs[sb_][edst]);     \
    } while (0)

    STAGE(0, 0);
    STAGE(1, 1);

    {   // ex_s: 2 gx rows x 4096 exps
        const float* pb = pos + (size_t)b * NN * 2;
        const float gx0 = (float)(mblk * 2)     * (1.0f / 63.0f);
        const float gx1 = (float)(mblk * 2 + 1) * (1.0f / 63.0f);
        for (int k = tid; k < NN; k += 512) {
            const float x = pb[2 * k];
            const float d0 = gx0 - x, d1 = gx1 - x;
            ex_s[0][k] = __float2half_rn(__expf(d0 * d0 * -50.0f));
            ex_s[1][k] = __float2half_rn(__expf(d1 * d1 * -50.0f));
        }
    }
    __syncthreads();   // prologue drain: stage(0), stage(1) landed; ex_s ready

    floatx16 acc00 = {}, acc01 = {}, acc10 = {}, acc11 = {};
    float s0 = 0.f, s1 = 0.f;

    const int rdO = kw * 1024 + lane * 8;     // frag base within round buf
    const __half* exg = ex_s[g];

    int sb = 0;
    for (int r = 0; r < 64; ++r) {
        if (r < 62) {
            const int s2 = (sb >= 1) ? sb - 1 : sb + 2;   // (sb+2)%3
            STAGE(r + 2, s2);
        }
        {
            const __half* eb_ = &EYs[sb][rdO];
            const __half* bb_ = &Bs[sb][rdO];
            half8 ey0 = *(const half8*)(eb_);
            half8 ey1 = *(const half8*)(eb_ + 512);
            half8 bf0 = *(const half8*)(bb_);
            half8 bf1 = *(const half8*)(bb_ + 512);
            half8 ex8 = *(const half8*)(exg + r * 64 + kw * 16 + hi8);
            half8 a0 = ex8 * ey0;
            half8 a1 = ex8 * ey1;
            s0 = sum8(a0, s0);
            s1 = sum8(a1, s1);
            __builtin_amdgcn_s_setprio(1);
            acc00 = MFMA32(a0, bf0, acc00);
            acc01 = MFMA32(a0, bf1, acc01);
            acc10 = MFMA32(a1, bf0, acc10);
            acc11 = MFMA32(a1, bf1, acc11);
            __builtin_amdgcn_s_setprio(0);
        }
        __builtin_amdgcn_sched_barrier(0);
        if (r < 62) { asm volatile("s_waitcnt vmcnt(2)" ::: "memory"); }
        else        { asm volatile("s_waitcnt vmcnt(0)" ::: "memory"); }
        __builtin_amdgcn_s_barrier();
        __builtin_amdgcn_sched_barrier(0);
        sb = (sb >= 2) ? 0 : sb + 1;
    }

    // ---- row-sum partials: wave (g,kw) covered k = r*64 + kw*16 + hi8 + j
    s0 += __shfl_xor(s0, 32, 64);
    s1 += __shfl_xor(s1, 32, 64);
    if (lane < 32) {
        S_s[kw][g * 64 + lane]      = s0;   // rt=0 rows
        S_s[kw][g * 64 + 32 + lane] = s1;   // rt=1 rows
    }
    __syncthreads();
    if (tid < 128)
        Sinv_s[tid] = 1.0f / (S_s[0][tid] + S_s[1][tid] + S_s[2][tid] + S_s[3][tid] + 1e-8f);

    // ---- cross-kw accumulator reduce (through Bs scratch) + normalize + store.
    // D layout: col(e)=lane&31, row = (reg&3) + 8*(reg>>2) + 4*(lane>>5)
    float* RS = (float*)&Bs[0][0];   // 6144 floats = 24 KB (2g x 3kw x 1024)

#define REDUCE_STORE(ACC, RT, EI) do {                                               \
        if (kw > 0) *(floatx16*)&RS[((g * 3) + (kw - 1)) * 1024 + lane * 16] = ACC;  \
        __syncthreads();                                                             \
        if (kw == 0) {                                                               \
            floatx16 t0 = *(const floatx16*)&RS[(g * 3 + 0) * 1024 + lane * 16];     \
            floatx16 t1 = *(const floatx16*)&RS[(g * 3 + 1) * 1024 + lane * 16];     \
            floatx16 t2 = *(const floatx16*)&RS[(g * 3 + 2) * 1024 + lane * 16];     \
            ACC += t0; ACC += t1; ACC += t2;                                         \
            const int e = et * 64 + (EI) * 32 + (lane & 31);                         \
            float* orow = out + ((size_t)b * NE + e) * NP                            \
                              + mblk * 128 + g * 64 + (RT) * 32;                     \
            _Pragma("unroll")                                                        \
            for (int q = 0; q < 4; ++q) {                                            \
                const int pr = q * 8 + ((lane >> 5) << 2);                           \
                const floatx4 sv = *(const floatx4*)&Sinv_s[g * 64 + (RT) * 32 + pr];\
                floatx4 o;                                                           \
                o.x = ACC[q * 4 + 0] * sv.x; o.y = ACC[q * 4 + 1] * sv.y;            \
                o.z = ACC[q * 4 + 2] * sv.z; o.w = ACC[q * 4 + 3] * sv.w;            \
                *(floatx4*)&orow[pr] = o;                                            \
            }                                                                        \
        }                                                                            \
        __syncthreads();                                                             \
    } while (0)

    REDUCE_STORE(acc00, 0, 0);
    REDUCE_STORE(acc01, 0, 1);
    REDUCE_STORE(acc10, 1, 0);
    REDUCE_STORE(acc11, 1, 1);

#undef REDUCE_STORE
#undef STAGE
}

extern "C" void kernel_launch(void* const* d_in, const int* in_sizes, int n_in,
                              void* d_out, int out_size, void* d_ws, size_t ws_size,
                              hipStream_t stream) {
    const float* feat = (const float*)d_in[0];   // [4][4096][256] f32
    const float* pos  = (const float*)d_in[1];   // [4][4096][2]  f32
    float* out = (float*)d_out;                  // [4][256][4096] f32
    __half* FT  = (__half*)d_ws;                                       // 8.39 MB (frag order)
    __half* EYf = (__half*)((char*)d_ws + (size_t)NB * NE * NN * 2);   // +2.10 MB (frag order)

    hipLaunchKernelGGL(feat_transpose, dim3(NN / 128, NE / 32, NB), dim3(256), 0, stream,
                       feat, FT);
    hipLaunchKernelGGL(eyf_kernel, dim3((NB << 18) / 256), dim3(256), 0, stream,
                       pos, EYf);
    hipLaunchKernelGGL(nw_gemm, dim3(512), dim3(512), 0, stream,
                       FT, EYf, pos, out);
}

// Round 4
// 117.148 us; speedup vs baseline: 1.1765x; 1.0945x over previous
//
#include <hip/hip_runtime.h>
#include <hip/hip_fp16.h>

// NeuronToSpatialGrid R6b (retry of R6 — container infra failure, kernel unchanged):
// register-pipelined rounds — ds_reads for round r+1 issue under round r's MFMAs
// (triple-buffered LDS, counted vmcnt, 1 barrier/round).
// 512 blocks x 512 thr (2 blocks/CU, 4 waves/SIMD, 2 barrier domains).
// prep kernel merges feat_transpose + eyf (3 launches -> 2).

typedef __attribute__((ext_vector_type(8))) _Float16 half8;
typedef __attribute__((ext_vector_type(2))) _Float16 half2v;
typedef __attribute__((ext_vector_type(4))) float floatx4;
typedef __attribute__((ext_vector_type(16))) float floatx16;

#define NB 4
#define NN 4096
#define NE 256
#define NP 4096

#if defined(__has_builtin)
#if __has_builtin(__builtin_amdgcn_fdot2)
#define HAVE_FDOT2 1
#endif
#endif

__device__ inline float sum8(half8 v, float s) {
#ifdef HAVE_FDOT2
    half2v one; one[0] = (_Float16)1.0f; one[1] = (_Float16)1.0f;
    half2v* p = (half2v*)&v;
#pragma unroll
    for (int j = 0; j < 4; j++) s = __builtin_amdgcn_fdot2(p[j], one, s, false);
#else
#pragma unroll
    for (int j = 0; j < 8; j++) s += (float)v[j];
#endif
    return s;
}

#define MFMA32(a, bb, c) __builtin_amdgcn_mfma_f32_32x32x16_f16(a, bb, c, 0, 0, 0)

__device__ __forceinline__ void gload_lds16(const void* g, void* l) {
    __builtin_amdgcn_global_load_lds((const __attribute__((address_space(1))) void*)g,
                                     (__attribute__((address_space(3))) void*)l, 16, 0, 0);
}

// ---------- prep: region [0,1024) = feat transpose; [1024,2048) = EY table.
// FT frag order: idx = (((b*256+kb)*8+eb)*64+l)*8+j = F[b][kb*16+(l>>5)*8+j][eb*32+(l&31)]
// EY frag order: idx = (((b*256+kb)*2+rt)*64+l)*8+j = exp(-50*(r/63-y_k)^2),
//   r = rt*32+(l&31), k = kb*16+(l>>5)*8+j
__global__ __launch_bounds__(256) void prep(const float* __restrict__ in,
                                            const float* __restrict__ pos,
                                            __half* __restrict__ ft,
                                            __half* __restrict__ EYf) {
    const int bb  = blockIdx.x;
    const int tid = threadIdx.x;
    if (bb < 1024) {
        __shared__ float tile[128][33];
        const int bx = bb & 31, eb2 = (bb >> 5) & 7, b = bb >> 8;
        const int n0 = bx * 128;
        const int rn = tid >> 3, re = (tid & 7) * 4;
#pragma unroll
        for (int p = 0; p < 4; p++) {
            const int n = p * 32 + rn;
            float4 v = *(const float4*)&in[(size_t)(b * NN + n0 + n) * NE + eb2 * 32 + re];
            tile[n][re] = v.x; tile[n][re + 1] = v.y; tile[n][re + 2] = v.z; tile[n][re + 3] = v.w;
        }
        __syncthreads();
#pragma unroll
        for (int i = 0; i < 2; i++) {
            const int c = i * 256 + tid;
            const int l = c & 63, kb_l = c >> 6;
            const int nbase = kb_l * 16 + ((l >> 5) << 3);
            const int col = l & 31;
            __half hh[8];
#pragma unroll
            for (int j = 0; j < 8; j++) hh[j] = __float2half_rn(tile[nbase + j][col]);
            const size_t idx = ((((size_t)b * 256 + (size_t)bx * 8 + kb_l) * 8 + eb2) * 64 + l) * 8;
            *(uint4*)&ft[idx] = *(const uint4*)hh;
        }
    } else {
        const int base = (bb - 1024) * 1024 + tid * 4;
        const int j0 = base & 7;
        const int l  = (base >> 3) & 63;
        const int rt = (base >> 9) & 1;
        const int kb = (base >> 10) & 255;
        const int b  = base >> 18;
        const int r  = rt * 32 + (l & 31);
        const int k0 = kb * 16 + ((l >> 5) << 3) + j0;
        const float ry = (float)r * (1.0f / 63.0f);
        __half hh[4];
#pragma unroll
        for (int jj = 0; jj < 4; jj++) {
            const float y = pos[((size_t)b * NN + k0 + jj) * 2 + 1];
            const float d = ry - y;
            hh[jj] = __float2half_rn(__expf(d * d * -50.0f));
        }
        *(uint2*)&EYf[base] = *(const uint2*)hh;
    }
}

// ---------- fused GEMM
__global__ __launch_bounds__(512, 4) void nw_gemm(const __half* __restrict__ FT,
                                                  const __half* __restrict__ EYf,
                                                  const float* __restrict__ pos,
                                                  float* __restrict__ out) {
    __shared__ __half Stage_s[2][3][4096];   // [0]=B tiles, [1]=EY tiles (48 KB)
    __shared__ __half ex_s[2][4096];         // 16 KB
    __shared__ float S_s[4][128];
    __shared__ float Sinv_s[128];

    const int bid  = blockIdx.x;
    const int xcd  = bid & 7;
    const int b    = xcd >> 1;
    const int etp  = xcd & 1;
    const int rest = bid >> 3;
    const int et   = etp * 2 + (rest & 1);   // e-quarter (64 e)
    const int mblk = rest >> 1;              // 0..31
    const int tid  = threadIdx.x;
    const int wave = tid >> 6, lane = tid & 63;
    const int g   = wave & 1;                // m-half
    const int kw  = wave >> 1;               // k-quarter
    const int kwo = kw * 16 + ((lane >> 5) << 3);

    __half (*Bsb)[4096] = Stage_s[0];
    __half (*Eyb)[4096] = Stage_s[1];

    const __half* ft_t = FT + ((size_t)(b * 256 + (tid >> 7)) * 8 + et * 2) * 512
                            + (size_t)(tid & 127) * 8;
    const __half* ey_t = EYf + ((size_t)b << 18) + (size_t)tid * 8;
    const int bdst = (tid >> 7) * 1024 + (tid & 127) * 8;
    const int edst = tid * 8;

#define STAGE(rr, d_) do {                                             \
        gload_lds16(ft_t + (size_t)(rr) * 16384, &Bsb[d_][bdst]);      \
        gload_lds16(ey_t + (size_t)(rr) * 4096,  &Eyb[d_][edst]);      \
    } while (0)

    STAGE(0, 0);
    STAGE(1, 1);

    {   // ex_s: 2 gx rows x 4096 exps
        const float* pb = pos + (size_t)b * NN * 2;
        const float gx0 = (float)(mblk * 2)     * (1.0f / 63.0f);
        const float gx1 = (float)(mblk * 2 + 1) * (1.0f / 63.0f);
        for (int k = tid; k < NN; k += 512) {
            const float x = pb[2 * k];
            const float d0 = gx0 - x, d1 = gx1 - x;
            ex_s[0][k] = __float2half_rn(__expf(d0 * d0 * -50.0f));
            ex_s[1][k] = __float2half_rn(__expf(d1 * d1 * -50.0f));
        }
    }
    __syncthreads();   // stage(0),(1) landed; ex_s ready

    floatx16 acc00 = {}, acc01 = {}, acc10 = {}, acc11 = {};
    float s0 = 0.f, s1 = 0.f;
    const int rdO = kw * 1024 + lane * 8;
    const __half* exg = ex_s[g];

    // prologue: frags(0) -> A-set
    half8 aA0, aA1, bfA0, bfA1, aB0, aB1, bfB0, bfB1, exN;
    {
        const __half* eb_ = &Eyb[0][rdO];
        const __half* bb_ = &Bsb[0][rdO];
        exN  = *(const half8*)(exg + kwo);
        aA0  = *(const half8*)(eb_);
        aA1  = *(const half8*)(eb_ + 512);
        bfA0 = *(const half8*)(bb_);
        bfA1 = *(const half8*)(bb_ + 512);
        aA0 *= exN; aA1 *= exN;
        s0 = sum8(aA0, s0); s1 = sum8(aA1, s1);
    }

    int sb = 0;
    for (int t = 0; t < 32; ++t) {
        const int sbn1 = (sb + 1 < 3) ? sb + 1 : sb - 2;
        const int sbn2 = (sb + 2 < 3) ? sb + 2 : sb - 1;

        // ---- round A (r = 2t): issue both stages for next pair; read frags(2t+1)
        if (t < 31) { STAGE(2 * t + 2, sbn2); STAGE(2 * t + 3, sb); }
        {
            const __half* eb_ = &Eyb[sbn1][rdO];
            const __half* bb_ = &Bsb[sbn1][rdO];
            exN  = *(const half8*)(exg + (2 * t + 1) * 64 + kwo);
            aB0  = *(const half8*)(eb_);
            aB1  = *(const half8*)(eb_ + 512);
            bfB0 = *(const half8*)(bb_);
            bfB1 = *(const half8*)(bb_ + 512);
        }
        __builtin_amdgcn_sched_barrier(0);
        __builtin_amdgcn_s_setprio(1);
        acc00 = MFMA32(aA0, bfA0, acc00);
        acc01 = MFMA32(aA0, bfA1, acc01);
        acc10 = MFMA32(aA1, bfA0, acc10);
        acc11 = MFMA32(aA1, bfA1, acc11);
        __builtin_amdgcn_s_setprio(0);
        aB0 *= exN; aB1 *= exN;
        s0 = sum8(aB0, s0); s1 = sum8(aB1, s1);
        if (t < 31) { asm volatile("s_waitcnt vmcnt(2)" ::: "memory"); }
        else        { asm volatile("s_waitcnt vmcnt(0)" ::: "memory"); }
        __builtin_amdgcn_s_barrier();

        // ---- round B (r = 2t+1): read frags(2t+2)
        if (t < 31) {
            const __half* eb_ = &Eyb[sbn2][rdO];
            const __half* bb_ = &Bsb[sbn2][rdO];
            exN  = *(const half8*)(exg + (2 * t + 2) * 64 + kwo);
            aA0  = *(const half8*)(eb_);
            aA1  = *(const half8*)(eb_ + 512);
            bfA0 = *(const half8*)(bb_);
            bfA1 = *(const half8*)(bb_ + 512);
        }
        __builtin_amdgcn_sched_barrier(0);
        __builtin_amdgcn_s_setprio(1);
        acc00 = MFMA32(aB0, bfB0, acc00);
        acc01 = MFMA32(aB0, bfB1, acc01);
        acc10 = MFMA32(aB1, bfB0, acc10);
        acc11 = MFMA32(aB1, bfB1, acc11);
        __builtin_amdgcn_s_setprio(0);
        if (t < 31) {
            aA0 *= exN; aA1 *= exN;
            s0 = sum8(aA0, s0); s1 = sum8(aA1, s1);
        }
        asm volatile("s_waitcnt vmcnt(0)" ::: "memory");
        __builtin_amdgcn_s_barrier();
        sb = sbn2;
    }

    // ---- row-sum partials (wave (g,kw) covered k = r*64 + kw*16 + hi8 + j)
    s0 += __shfl_xor(s0, 32, 64);
    s1 += __shfl_xor(s1, 32, 64);
    if (lane < 32) {
        S_s[kw][g * 64 + lane]      = s0;
        S_s[kw][g * 64 + 32 + lane] = s1;
    }

    // ---- k-split reduce through freed staging LDS (2 passes x 2 quadrants)
    float* RS = (float*)&Stage_s[0][0][0];   // 12288 floats

#define RSWRITE(A0_, A1_) do {                                                    \
        if (kw > 0) {                                                             \
            *(floatx16*)&RS[((0 * 2 + g) * 3 + (kw - 1)) * 1024 + lane * 16] = A0_; \
            *(floatx16*)&RS[((1 * 2 + g) * 3 + (kw - 1)) * 1024 + lane * 16] = A1_; \
        }                                                                         \
    } while (0)

#define RSREDUCE(A0_, A1_, RT_) do {                                              \
        if (kw == 0) {                                                            \
            _Pragma("unroll")                                                     \
            for (int qq = 0; qq < 2; qq++) {                                      \
                floatx16 a = qq ? A1_ : A0_;                                      \
                const int rb = ((qq * 2 + g) * 3) * 1024 + lane * 16;             \
                a += *(const floatx16*)&RS[rb];                                   \
                a += *(const floatx16*)&RS[rb + 1024];                            \
                a += *(const floatx16*)&RS[rb + 2048];                            \
                const int e = et * 64 + qq * 32 + (lane & 31);                    \
                float* orow = out + ((size_t)b * NE + e) * NP                     \
                                  + mblk * 128 + g * 64 + (RT_) * 32;             \
                _Pragma("unroll")                                                 \
                for (int q = 0; q < 4; ++q) {                                     \
                    const int pr = q * 8 + ((lane >> 5) << 2);                    \
                    const floatx4 sv = *(const floatx4*)&Sinv_s[g * 64 + (RT_) * 32 + pr]; \
                    floatx4 o;                                                    \
                    o.x = a[q * 4 + 0] * sv.x; o.y = a[q * 4 + 1] * sv.y;         \
                    o.z = a[q * 4 + 2] * sv.z; o.w = a[q * 4 + 3] * sv.w;         \
                    *(floatx4*)&orow[pr] = o;                                     \
                }                                                                 \
            }                                                                     \
        }                                                                         \
    } while (0)

    RSWRITE(acc00, acc01);
    __syncthreads();
    if (tid < 128)
        Sinv_s[tid] = 1.0f / (S_s[0][tid] + S_s[1][tid] + S_s[2][tid] + S_s[3][tid] + 1e-8f);
    __syncthreads();
    RSREDUCE(acc00, acc01, 0);
    __syncthreads();
    RSWRITE(acc10, acc11);
    __syncthreads();
    RSREDUCE(acc10, acc11, 1);

#undef RSWRITE
#undef RSREDUCE
#undef STAGE
}

extern "C" void kernel_launch(void* const* d_in, const int* in_sizes, int n_in,
                              void* d_out, int out_size, void* d_ws, size_t ws_size,
                              hipStream_t stream) {
    const float* feat = (const float*)d_in[0];   // [4][4096][256] f32
    const float* pos  = (const float*)d_in[1];   // [4][4096][2]  f32
    float* out = (float*)d_out;                  // [4][256][4096] f32
    __half* FT  = (__half*)d_ws;                                       // 8.39 MB (frag order)
    __half* EYf = (__half*)((char*)d_ws + (size_t)NB * NE * NN * 2);   // +2.10 MB (frag order)

    hipLaunchKernelGGL(prep, dim3(2048), dim3(256), 0, stream, feat, pos, FT, EYf);
    hipLaunchKernelGGL(nw_gemm, dim3(512), dim3(512), 0, stream, FT, EYf, pos, out);
}

// Round 5
// 116.038 us; speedup vs baseline: 1.1878x; 1.0096x over previous
//
#include <hip/hip_runtime.h>
#include <hip/hip_fp16.h>

// NeuronToSpatialGrid R7: EY A-frags loaded straight from global (L2) into regs —
// no LDS round-trip; LDS carries only the shared B (feature) tiles.
// Per round/CU LDS drops 1344->~770 cyc (was the binding pipe at R6).
// 512 blocks x 512 thr (2 blocks/CU, 4 waves/SIMD), triple-buffered B staging,
// counted vmcnt(2) per round (ey prefetch rides across the barrier).

typedef __attribute__((ext_vector_type(8))) _Float16 half8;
typedef __attribute__((ext_vector_type(2))) _Float16 half2v;
typedef __attribute__((ext_vector_type(4))) float floatx4;
typedef __attribute__((ext_vector_type(16))) float floatx16;

#define NB 4
#define NN 4096
#define NE 256
#define NP 4096

#if defined(__has_builtin)
#if __has_builtin(__builtin_amdgcn_fdot2)
#define HAVE_FDOT2 1
#endif
#endif

__device__ inline float sum8(half8 v, float s) {
#ifdef HAVE_FDOT2
    half2v one; one[0] = (_Float16)1.0f; one[1] = (_Float16)1.0f;
    half2v* p = (half2v*)&v;
#pragma unroll
    for (int j = 0; j < 4; j++) s = __builtin_amdgcn_fdot2(p[j], one, s, false);
#else
#pragma unroll
    for (int j = 0; j < 8; j++) s += (float)v[j];
#endif
    return s;
}

#define MFMA32(a, bb, c) __builtin_amdgcn_mfma_f32_32x32x16_f16(a, bb, c, 0, 0, 0)

__device__ __forceinline__ void gload_lds16(const void* g, void* l) {
    __builtin_amdgcn_global_load_lds((const __attribute__((address_space(1))) void*)g,
                                     (__attribute__((address_space(3))) void*)l, 16, 0, 0);
}

// ---------- prep: region [0,1024) = feat transpose; [1024,2048) = EY table.
// FT frag order: idx = (((b*256+kb)*8+eb)*64+l)*8+j = F[b][kb*16+(l>>5)*8+j][eb*32+(l&31)]
// EY frag order: idx = (((b*256+kb)*2+rt)*64+l)*8+j = exp(-50*(r/63-y_k)^2),
//   r = rt*32+(l&31), k = kb*16+(l>>5)*8+j
__global__ __launch_bounds__(256) void prep(const float* __restrict__ in,
                                            const float* __restrict__ pos,
                                            __half* __restrict__ ft,
                                            __half* __restrict__ EYf) {
    const int bb  = blockIdx.x;
    const int tid = threadIdx.x;
    if (bb < 1024) {
        __shared__ float tile[128][33];
        const int bx = bb & 31, eb2 = (bb >> 5) & 7, b = bb >> 8;
        const int n0 = bx * 128;
        const int rn = tid >> 3, re = (tid & 7) * 4;
#pragma unroll
        for (int p = 0; p < 4; p++) {
            const int n = p * 32 + rn;
            float4 v = *(const float4*)&in[(size_t)(b * NN + n0 + n) * NE + eb2 * 32 + re];
            tile[n][re] = v.x; tile[n][re + 1] = v.y; tile[n][re + 2] = v.z; tile[n][re + 3] = v.w;
        }
        __syncthreads();
#pragma unroll
        for (int i = 0; i < 2; i++) {
            const int c = i * 256 + tid;
            const int l = c & 63, kb_l = c >> 6;
            const int nbase = kb_l * 16 + ((l >> 5) << 3);
            const int col = l & 31;
            __half hh[8];
#pragma unroll
            for (int j = 0; j < 8; j++) hh[j] = __float2half_rn(tile[nbase + j][col]);
            const size_t idx = ((((size_t)b * 256 + (size_t)bx * 8 + kb_l) * 8 + eb2) * 64 + l) * 8;
            *(uint4*)&ft[idx] = *(const uint4*)hh;
        }
    } else {
        const int base = (bb - 1024) * 1024 + tid * 4;
        const int j0 = base & 7;
        const int l  = (base >> 3) & 63;
        const int rt = (base >> 9) & 1;
        const int kb = (base >> 10) & 255;
        const int b  = base >> 18;
        const int r  = rt * 32 + (l & 31);
        const int k0 = kb * 16 + ((l >> 5) << 3) + j0;
        const float ry = (float)r * (1.0f / 63.0f);
        __half hh[4];
#pragma unroll
        for (int jj = 0; jj < 4; jj++) {
            const float y = pos[((size_t)b * NN + k0 + jj) * 2 + 1];
            const float d = ry - y;
            hh[jj] = __float2half_rn(__expf(d * d * -50.0f));
        }
        *(uint2*)&EYf[base] = *(const uint2*)hh;
    }
}

// ---------- fused GEMM
// Per-round VMEM issue order (pinned by sched_barrier): [glds(r+2)] .. [ey(r+2)x2].
// End-of-round asm vmcnt(2): leaves ey(r+2)x2 in flight, forces glds(r+2) (needed
// by round r+1's ds_reads) + everything older. Compiler's own wait before the
// a-compute (ey(r+1) use) is vmcnt(1) -> glds(r+2) stays in flight there too.
__global__ __launch_bounds__(512, 4) void nw_gemm(const __half* __restrict__ FT,
                                                  const __half* __restrict__ EYf,
                                                  const float* __restrict__ pos,
                                                  float* __restrict__ out) {
    __shared__ __align__(64) char pool[49152];   // run: Bs 3x8KB + ex 16KB; epi: RS 48KB
    __shared__ float S_s[4][128];
    __shared__ float Sinv_s[128];

    __half* Bs0 = (__half*)pool;                  // 3 x 4096 halfs
    __half* Bs1 = Bs0 + 4096;
    __half* Bs2 = Bs0 + 8192;
    __half* exb = Bs0 + 12288;                    // 2 x 4096 halfs

    const int bid  = blockIdx.x;
    const int xcd  = bid & 7;            // pin (b, e-half): FT-half 1MB + EY 512KB in L2
    const int b    = xcd >> 1;
    const int etp  = xcd & 1;
    const int rest = bid >> 3;
    const int et   = etp * 2 + (rest & 1);   // e-quarter (64 e)
    const int mblk = rest >> 1;              // 0..31
    const int tid  = threadIdx.x;
    const int wave = tid >> 6, lane = tid & 63;
    const int g   = wave & 1;                // m-half (gx = 2*mblk + g)
    const int kw  = wave >> 1;               // k-quarter
    const int kwo = kw * 16 + ((lane >> 5) << 3);

    const __half* ft_t = FT + ((size_t)(b * 256 + (tid >> 7)) * 8 + et * 2) * 512
                            + (size_t)(tid & 127) * 8;
    const __half* eyW = EYf + ((size_t)b << 18) + (size_t)lane * 8;
    const int bdst = (tid >> 7) * 1024 + (tid & 127) * 8;
    const int rdO  = kw * 1024 + lane * 8;
    const __half* exg = exb + g * 4096;

    // ---- prologue: stage B(0),B(1); load ey(0); build ex_s; full drain
    gload_lds16(ft_t,          Bs0 + bdst);
    gload_lds16(ft_t + 16384,  Bs1 + bdst);
    half8 ey00 = *(const half8*)(eyW + (size_t)((kw * 2    ) * 512));
    half8 ey01 = *(const half8*)(eyW + (size_t)((kw * 2 + 1) * 512));
    {
        const float* pb = pos + (size_t)b * NN * 2;
        const float gx0 = (float)(mblk * 2)     * (1.0f / 63.0f);
        const float gx1 = (float)(mblk * 2 + 1) * (1.0f / 63.0f);
        for (int k = tid; k < NN; k += 512) {
            const float x = pb[2 * k];
            const float d0 = gx0 - x, d1 = gx1 - x;
            exb[k]        = __float2half_rn(__expf(d0 * d0 * -50.0f));
            exb[4096 + k] = __float2half_rn(__expf(d1 * d1 * -50.0f));
        }
    }
    __syncthreads();   // stage(0),(1), ey(0) landed; ex ready

    floatx16 acc00 = {}, acc01 = {}, acc10 = {}, acc11 = {};
    float s0 = 0.f, s1 = 0.f;

    half8 aA0, aA1, bfA0, bfA1, aB0, aB1, bfB0, bfB1, eyN0, eyN1, exN;

    // frags(0): bf from Bs0, a(0) = ex(0)*ey(0)
    bfA0 = *(const half8*)(Bs0 + rdO);
    bfA1 = *(const half8*)(Bs0 + rdO + 512);
    {
        half8 ex0 = *(const half8*)(exg + kwo);
        aA0 = ex0 * ey00; aA1 = ex0 * ey01;
        s0 = sum8(aA0, s0); s1 = sum8(aA1, s1);
    }
    // ey(1) prefetch (consumed at bottom of round 0)
    eyN0 = *(const half8*)(eyW + (size_t)(((1 * 4 + kw) * 2    ) * 512));
    eyN1 = *(const half8*)(eyW + (size_t)(((1 * 4 + kw) * 2 + 1) * 512));

#define ROUND(r_, RB, SB_, cA0,cA1,cB0,cB1, nA0,nA1,nB0,nB1) do {              \
    if ((r_) < 62) gload_lds16(ft_t + (size_t)((r_) + 2) * 16384, (SB_) + bdst); \
    __builtin_amdgcn_sched_barrier(0);                                         \
    if ((r_) < 63) {                                                           \
        nB0 = *(const half8*)((RB) + rdO);                                     \
        nB1 = *(const half8*)((RB) + rdO + 512);                               \
        exN = *(const half8*)(exg + ((r_) + 1) * 64 + kwo);                    \
    }                                                                          \
    __builtin_amdgcn_s_setprio(1);                                             \
    acc00 = MFMA32(cA0, cB0, acc00);                                           \
    acc01 = MFMA32(cA0, cB1, acc01);                                           \
    acc10 = MFMA32(cA1, cB0, acc10);                                           \
    acc11 = MFMA32(cA1, cB1, acc11);                                           \
    __builtin_amdgcn_s_setprio(0);                                             \
    if ((r_) < 63) {                                                           \
        nA0 = exN * eyN0; nA1 = exN * eyN1;                                    \
        s0 = sum8(nA0, s0); s1 = sum8(nA1, s1);                                \
    }                                                                          \
    __builtin_amdgcn_sched_barrier(0);                                         \
    {                                                                          \
        const int rn2_ = ((r_) + 2) & 63;                                      \
        eyN0 = *(const half8*)(eyW + (size_t)(((rn2_ * 4 + kw) * 2    ) * 512)); \
        eyN1 = *(const half8*)(eyW + (size_t)(((rn2_ * 4 + kw) * 2 + 1) * 512)); \
    }                                                                          \
    __builtin_amdgcn_sched_barrier(0);                                         \
    if ((r_) < 63) { asm volatile("s_waitcnt vmcnt(2)" ::: "memory"); }        \
    else           { asm volatile("s_waitcnt vmcnt(0)" ::: "memory"); }        \
    __builtin_amdgcn_s_barrier();                                              \
} while (0)

    __half *px = Bs0, *py = Bs1, *pz = Bs2;
    for (int t = 0; t < 32; ++t) {
        const int r0 = 2 * t;
        ROUND(r0,     py, pz, aA0,aA1,bfA0,bfA1, aB0,aB1,bfB0,bfB1);
        ROUND(r0 + 1, pz, px, aB0,aB1,bfB0,bfB1, aA0,aA1,bfA0,bfA1);
        __half* tmp = pz; pz = py; py = px; px = tmp;   // (x,y,z) <- (z,x,y)
    }
#undef ROUND

    // ---- row-sum partials (wave (g,kw) covered k = r*64 + kw*16 + hi8 + j)
    s0 += __shfl_xor(s0, 32, 64);
    s1 += __shfl_xor(s1, 32, 64);
    if (lane < 32) {
        S_s[kw][g * 64 + lane]      = s0;
        S_s[kw][g * 64 + 32 + lane] = s1;
    }

    // ---- k-split reduce through the freed pool (48 KB) + normalize + store
    float* RS = (float*)pool;   // 12288 floats

#define RSWRITE(A0_, A1_) do {                                                    \
        if (kw > 0) {                                                             \
            *(floatx16*)&RS[((0 * 2 + g) * 3 + (kw - 1)) * 1024 + lane * 16] = A0_; \
            *(floatx16*)&RS[((1 * 2 + g) * 3 + (kw - 1)) * 1024 + lane * 16] = A1_; \
        }                                                                         \
    } while (0)

#define RSREDUCE(A0_, A1_, RT_) do {                                              \
        if (kw == 0) {                                                            \
            _Pragma("unroll")                                                     \
            for (int qq = 0; qq < 2; qq++) {                                      \
                floatx16 a = qq ? A1_ : A0_;                                      \
                const int rb = ((qq * 2 + g) * 3) * 1024 + lane * 16;             \
                a += *(const floatx16*)&RS[rb];                                   \
                a += *(const floatx16*)&RS[rb + 1024];                            \
                a += *(const floatx16*)&RS[rb + 2048];                            \
                const int e = et * 64 + qq * 32 + (lane & 31);                    \
                float* orow = out + ((size_t)b * NE + e) * NP                     \
                                  + mblk * 128 + g * 64 + (RT_) * 32;             \
                _Pragma("unroll")                                                 \
                for (int q = 0; q < 4; ++q) {                                     \
                    const int pr = q * 8 + ((lane >> 5) << 2);                    \
                    const floatx4 sv = *(const floatx4*)&Sinv_s[g * 64 + (RT_) * 32 + pr]; \
                    floatx4 o;                                                    \
                    o.x = a[q * 4 + 0] * sv.x; o.y = a[q * 4 + 1] * sv.y;         \
                    o.z = a[q * 4 + 2] * sv.z; o.w = a[q * 4 + 3] * sv.w;         \
                    *(floatx4*)&orow[pr] = o;                                     \
                }                                                                 \
            }                                                                     \
        }                                                                         \
    } while (0)

    RSWRITE(acc00, acc01);
    __syncthreads();
    if (tid < 128)
        Sinv_s[tid] = 1.0f / (S_s[0][tid] + S_s[1][tid] + S_s[2][tid] + S_s[3][tid] + 1e-8f);
    __syncthreads();
    RSREDUCE(acc00, acc01, 0);
    __syncthreads();
    RSWRITE(acc10, acc11);
    __syncthreads();
    RSREDUCE(acc10, acc11, 1);

#undef RSWRITE
#undef RSREDUCE
}

extern "C" void kernel_launch(void* const* d_in, const int* in_sizes, int n_in,
                              void* d_out, int out_size, void* d_ws, size_t ws_size,
                              hipStream_t stream) {
    const float* feat = (const float*)d_in[0];   // [4][4096][256] f32
    const float* pos  = (const float*)d_in[1];   // [4][4096][2]  f32
    float* out = (float*)d_out;                  // [4][256][4096] f32
    __half* FT  = (__half*)d_ws;                                       // 8.39 MB (frag order)
    __half* EYf = (__half*)((char*)d_ws + (size_t)NB * NE * NN * 2);   // +2.10 MB (frag order)

    hipLaunchKernelGGL(prep, dim3(2048), dim3(256), 0, stream, feat, pos, FT, EYf);
    hipLaunchKernelGGL(nw_gemm, dim3(512), dim3(512), 0, stream, FT, EYf, pos, out);
}